// Round 4
// baseline (281.047 us; speedup 1.0000x reference)
//
#include <hip/hip_runtime.h>

// Problem shape (fixed by setup_inputs): B=2, C=4, D=128, H=192, W=192
#define NB 2
#define NC 4
#define NS (128 * 192 * 192)      // spatial voxels per batch = 4718592
#define NTOT (NB * NS)            // 9437184
#define NSQ (NS / 4)              // float4-quads per batch = 1179648
#define EPSF 1e-8f
#define INF_BITS 0x7F800000u

// Launch geometry — compile-time so the K-loop fully unrolls with no
// runtime trip count (that's what let the compiler serialize R3's loads).
#define BLOCKS 2304
#define TPB 256
#define HALF (BLOCKS / 2)          // 1152 blocks per batch
#define STRIDE (HALF * TPB)        // 294912 quads per sweep
#define ITERS (NSQ / STRIDE)       // exactly 4

// Decomposition: loss = -(R0 + sum_{b,j} s_bj*(P_bj - mn_bj*Q_bj)) / NTOT
//   P_bj = sum z_j*(a_j-lse), Q_bj = sum (a_j-lse), R0 = sum (t==0)*(a_0-lse)
// ws layout: per-block partials, 16 floats per block (13 used), NO atomics.
//   [0..2]=mn1..3  [3..5]=mx1..3  [6..8]=P1..3  [9..11]=Q1..3  [12]=R0

__global__ __launch_bounds__(TPB, 4)
void k_fused(const float* __restrict__ x,
             const int* __restrict__ tgt,
             const float* __restrict__ dist,
             float* __restrict__ part) {
    const int b = (blockIdx.x >= HALF) ? 1 : 0;
    const int bid = blockIdx.x - b * HALF;

    const int4* t4 = (const int4*)tgt + (size_t)b * NSQ;
    const float4* d4 = (const float4*)dist + (size_t)b * NSQ;
    const float4* xb = (const float4*)x + (size_t)b * NC * NSQ;

    const int q0 = bid * TPB + threadIdx.x;

    float mn1 = __uint_as_float(INF_BITS), mn2 = mn1, mn3 = mn1;
    float mx1 = 0.f, mx2 = 0.f, mx3 = 0.f;
    float P1 = 0.f, P2 = 0.f, P3 = 0.f;
    float Q1 = 0.f, Q2 = 0.f, Q3 = 0.f;
    float R0 = 0.f;

    auto vox = [&](float a0, float a1, float a2, float a3, int tt, float dv) {
        float m = fmaxf(fmaxf(a0, a1), fmaxf(a2, a3));
        float e = __expf(a0 - m) + __expf(a1 - m) + __expf(a2 - m) + __expf(a3 - m);
        float lse = m + __logf(e);
        float z1 = (tt == 1) ? dv : 0.f;
        float z2 = (tt == 2) ? dv : 0.f;
        float z3 = (tt == 3) ? dv : 0.f;
        mn1 = fminf(mn1, z1); mx1 = fmaxf(mx1, z1);
        mn2 = fminf(mn2, z2); mx2 = fmaxf(mx2, z2);
        mn3 = fminf(mn3, z3); mx3 = fmaxf(mx3, z3);
        float l1 = a1 - lse, l2 = a2 - lse, l3 = a3 - lse;
        P1 += z1 * l1; P2 += z2 * l2; P3 += z3 * l3;
        Q1 += l1; Q2 += l2; Q3 += l3;
        R0 += (tt == 0) ? (a0 - lse) : 0.f;
    };

    // Prologue: issue iteration 0's 6 loads.
    float4 cx0 = xb[q0];
    float4 cx1 = xb[q0 + NSQ];
    float4 cx2 = xb[q0 + 2 * NSQ];
    float4 cx3 = xb[q0 + 3 * NSQ];
    int4 ct = t4[q0];
    float4 cd = d4[q0];

#pragma unroll
    for (int i = 0; i < ITERS; i++) {
        float4 nx0, nx1, nx2, nx3, nd;
        int4 nt;
        if (i + 1 < ITERS) {   // compile-time folded (full unroll)
            const int qn = q0 + (i + 1) * STRIDE;
            nx0 = xb[qn];
            nx1 = xb[qn + NSQ];
            nx2 = xb[qn + 2 * NSQ];
            nx3 = xb[qn + 3 * NSQ];
            nt = t4[qn];
            nd = d4[qn];
        }
        vox(cx0.x, cx1.x, cx2.x, cx3.x, ct.x, cd.x);
        vox(cx0.y, cx1.y, cx2.y, cx3.y, ct.y, cd.y);
        vox(cx0.z, cx1.z, cx2.z, cx3.z, ct.z, cd.z);
        vox(cx0.w, cx1.w, cx2.w, cx3.w, ct.w, cd.w);
        if (i + 1 < ITERS) {
            cx0 = nx0; cx1 = nx1; cx2 = nx2; cx3 = nx3; ct = nt; cd = nd;
        }
    }

    // wave(64) butterfly over the 13 accumulators
    for (int off = 32; off; off >>= 1) {
        mn1 = fminf(mn1, __shfl_down(mn1, off, 64));
        mn2 = fminf(mn2, __shfl_down(mn2, off, 64));
        mn3 = fminf(mn3, __shfl_down(mn3, off, 64));
        mx1 = fmaxf(mx1, __shfl_down(mx1, off, 64));
        mx2 = fmaxf(mx2, __shfl_down(mx2, off, 64));
        mx3 = fmaxf(mx3, __shfl_down(mx3, off, 64));
        P1 += __shfl_down(P1, off, 64);
        P2 += __shfl_down(P2, off, 64);
        P3 += __shfl_down(P3, off, 64);
        Q1 += __shfl_down(Q1, off, 64);
        Q2 += __shfl_down(Q2, off, 64);
        Q3 += __shfl_down(Q3, off, 64);
        R0 += __shfl_down(R0, off, 64);
    }

    __shared__ float sv[4][13];
    const int wid = threadIdx.x >> 6;
    if ((threadIdx.x & 63) == 0) {
        sv[wid][0] = mn1; sv[wid][1] = mn2; sv[wid][2] = mn3;
        sv[wid][3] = mx1; sv[wid][4] = mx2; sv[wid][5] = mx3;
        sv[wid][6] = P1;  sv[wid][7] = P2;  sv[wid][8] = P3;
        sv[wid][9] = Q1;  sv[wid][10] = Q2; sv[wid][11] = Q3;
        sv[wid][12] = R0;
    }
    __syncthreads();
    const int i = threadIdx.x;
    if (i < 13) {
        float v = sv[0][i];
        if (i < 3)      v = fminf(fminf(v, sv[1][i]), fminf(sv[2][i], sv[3][i]));
        else if (i < 6) v = fmaxf(fmaxf(v, sv[1][i]), fmaxf(sv[2][i], sv[3][i]));
        else            v = v + sv[1][i] + sv[2][i] + sv[3][i];
        part[(size_t)blockIdx.x * 16 + i] = v;   // plain store — NO atomics
    }
}

// One block reduces the 2304 x 13 partials and emits the scalar loss.
// Threads 0..127 own batch-0 rows (stride 128), 128..255 own batch-1 rows,
// so waves 0-1 hold only batch-0 data and waves 2-3 only batch-1.
__global__ __launch_bounds__(256, 1)
void k_final(const float* __restrict__ part, float* __restrict__ out) {
    const int t = threadIdx.x;
    const int batch = t >> 7;
    const int lane7 = t & 127;

    float mn[3] = {__uint_as_float(INF_BITS), __uint_as_float(INF_BITS), __uint_as_float(INF_BITS)};
    float mx[3] = {0.f, 0.f, 0.f};
    double P[3] = {0, 0, 0}, Q[3] = {0, 0, 0}, R0 = 0;

    for (int k = 0; k < HALF / 128; k++) {   // 9 rows per thread
        const float* r = part + (size_t)(batch * HALF + k * 128 + lane7) * 16;
#pragma unroll
        for (int j = 0; j < 3; j++) {
            mn[j] = fminf(mn[j], r[j]);
            mx[j] = fmaxf(mx[j], r[3 + j]);
            P[j] += (double)r[6 + j];
            Q[j] += (double)r[9 + j];
        }
        R0 += (double)r[12];
    }

    // wave(64) butterfly (each wave is single-batch)
    for (int off = 32; off; off >>= 1) {
#pragma unroll
        for (int j = 0; j < 3; j++) {
            mn[j] = fminf(mn[j], __shfl_down(mn[j], off, 64));
            mx[j] = fmaxf(mx[j], __shfl_down(mx[j], off, 64));
            P[j] += __shfl_down(P[j], off, 64);
            Q[j] += __shfl_down(Q[j], off, 64);
        }
        R0 += __shfl_down(R0, off, 64);
    }

    __shared__ float smn[4][3], smx[4][3];
    __shared__ double sP[4][3], sQ[4][3], sR[4];
    const int wid = t >> 6;
    if ((t & 63) == 0) {
#pragma unroll
        for (int j = 0; j < 3; j++) {
            smn[wid][j] = mn[j]; smx[wid][j] = mx[j];
            sP[wid][j] = P[j];   sQ[wid][j] = Q[j];
        }
        sR[wid] = R0;
    }
    __syncthreads();
    if (t == 0) {
        double acc = 0.0;
#pragma unroll
        for (int b = 0; b < 2; b++) {
            const int w0 = 2 * b, w1 = 2 * b + 1;
            acc += sR[w0] + sR[w1];
#pragma unroll
            for (int j = 0; j < 3; j++) {
                float mnf = fminf(smn[w0][j], smn[w1][j]);
                float mxf = fmaxf(smx[w0][j], smx[w1][j]);
                float sf = 1.0f / (mxf + EPSF - mnf);   // mirror reference fp32 scale
                acc += (double)sf * ((sP[w0][j] + sP[w1][j]) - (double)mnf * (sQ[w0][j] + sQ[w1][j]));
            }
        }
        out[0] = (float)(-acc / (double)NTOT);
    }
}

extern "C" void kernel_launch(void* const* d_in, const int* in_sizes, int n_in,
                              void* d_out, int out_size, void* d_ws, size_t ws_size,
                              hipStream_t stream) {
    const float* net = (const float*)d_in[0];   // [B, C, D, H, W] fp32
    const int* tgt = (const int*)d_in[1];       // [B, 1, D, H, W] int
    const float* dist = (const float*)d_in[2];  // [B, D, H, W] fp32
    float* part = (float*)d_ws;                 // 2304 x 16 floats = 147 KB

    k_fused<<<BLOCKS, TPB, 0, stream>>>(net, tgt, dist, part);
    k_final<<<1, 256, 0, stream>>>(part, (float*)d_out);
}

// Round 5
// 270.334 us; speedup vs baseline: 1.0396x; 1.0396x over previous
//
#include <hip/hip_runtime.h>

// Problem shape (fixed by setup_inputs): B=2, C=4, D=128, H=192, W=192
#define NB 2
#define NC 4
#define NS (128 * 192 * 192)      // spatial voxels per batch = 4718592
#define NTOT (NB * NS)            // 9437184
#define NSQ (NS / 4)              // float4-quads per batch = 1179648
#define EPSF 1e-8f
#define INF_BITS 0x7F800000u

// Geometry: 2 quads per thread, NO loop, all loads issued up-front.
#define BLOCKS 4608
#define TPB 256
#define HALFB (BLOCKS / 2)         // 2304 blocks per batch
#define STRIDE (HALFB * TPB)       // 589824 = NSQ/2

// Decomposition: loss = -(R0 + sum_{b,j} s_bj*(P_bj - mn_bj*Q_bj)) / NTOT
//   P_bj = sum z_j*(a_j-lse), Q_bj = sum (a_j-lse), R0 = sum (t==0)*(a_0-lse)
// part layout: 16 floats per block: [0..2]=mn [3..5]=mx [6..8]=P [9..11]=Q [12]=R0

__global__ void k_fused(const float* __restrict__ x,
                        const int* __restrict__ tgt,
                        const float* __restrict__ dist,
                        float* __restrict__ part) {
    const int b = (blockIdx.x >= HALFB) ? 1 : 0;
    const int bid = blockIdx.x - b * HALFB;
    const int q0 = bid * TPB + threadIdx.x;
    const int q1 = q0 + STRIDE;

    const int4* t4 = (const int4*)tgt + (size_t)b * NSQ;
    const float4* d4 = (const float4*)dist + (size_t)b * NSQ;
    const float4* xb = (const float4*)x + (size_t)b * NC * NSQ;

    // 12 independent vector loads — no inter-load dependencies, no loop,
    // no register reuse forcing early waits. ~64 VGPRs of data in flight.
    float4 ax0 = xb[q0];
    float4 ax1 = xb[q0 + NSQ];
    float4 ax2 = xb[q0 + 2 * NSQ];
    float4 ax3 = xb[q0 + 3 * NSQ];
    float4 bx0 = xb[q1];
    float4 bx1 = xb[q1 + NSQ];
    float4 bx2 = xb[q1 + 2 * NSQ];
    float4 bx3 = xb[q1 + 3 * NSQ];
    int4 at = t4[q0];
    int4 bt = t4[q1];
    float4 ad = d4[q0];
    float4 bd = d4[q1];

    float mn1 = __uint_as_float(INF_BITS), mn2 = mn1, mn3 = mn1;
    float mx1 = 0.f, mx2 = 0.f, mx3 = 0.f;
    float P1 = 0.f, P2 = 0.f, P3 = 0.f;
    float Q1 = 0.f, Q2 = 0.f, Q3 = 0.f;
    float R0 = 0.f;

    auto vox = [&](float a0, float a1, float a2, float a3, int tt, float dv) {
        float m = fmaxf(fmaxf(a0, a1), fmaxf(a2, a3));
        float e = __expf(a0 - m) + __expf(a1 - m) + __expf(a2 - m) + __expf(a3 - m);
        float lse = m + __logf(e);
        float z1 = (tt == 1) ? dv : 0.f;
        float z2 = (tt == 2) ? dv : 0.f;
        float z3 = (tt == 3) ? dv : 0.f;
        mn1 = fminf(mn1, z1); mx1 = fmaxf(mx1, z1);
        mn2 = fminf(mn2, z2); mx2 = fmaxf(mx2, z2);
        mn3 = fminf(mn3, z3); mx3 = fmaxf(mx3, z3);
        float l1 = a1 - lse, l2 = a2 - lse, l3 = a3 - lse;
        P1 += z1 * l1; P2 += z2 * l2; P3 += z3 * l3;
        Q1 += l1; Q2 += l2; Q3 += l3;
        R0 += (tt == 0) ? (a0 - lse) : 0.f;
    };

    vox(ax0.x, ax1.x, ax2.x, ax3.x, at.x, ad.x);
    vox(ax0.y, ax1.y, ax2.y, ax3.y, at.y, ad.y);
    vox(ax0.z, ax1.z, ax2.z, ax3.z, at.z, ad.z);
    vox(ax0.w, ax1.w, ax2.w, ax3.w, at.w, ad.w);
    vox(bx0.x, bx1.x, bx2.x, bx3.x, bt.x, bd.x);
    vox(bx0.y, bx1.y, bx2.y, bx3.y, bt.y, bd.y);
    vox(bx0.z, bx1.z, bx2.z, bx3.z, bt.z, bd.z);
    vox(bx0.w, bx1.w, bx2.w, bx3.w, bt.w, bd.w);

    // wave(64) butterfly over the 13 accumulators
    for (int off = 32; off; off >>= 1) {
        mn1 = fminf(mn1, __shfl_down(mn1, off, 64));
        mn2 = fminf(mn2, __shfl_down(mn2, off, 64));
        mn3 = fminf(mn3, __shfl_down(mn3, off, 64));
        mx1 = fmaxf(mx1, __shfl_down(mx1, off, 64));
        mx2 = fmaxf(mx2, __shfl_down(mx2, off, 64));
        mx3 = fmaxf(mx3, __shfl_down(mx3, off, 64));
        P1 += __shfl_down(P1, off, 64);
        P2 += __shfl_down(P2, off, 64);
        P3 += __shfl_down(P3, off, 64);
        Q1 += __shfl_down(Q1, off, 64);
        Q2 += __shfl_down(Q2, off, 64);
        Q3 += __shfl_down(Q3, off, 64);
        R0 += __shfl_down(R0, off, 64);
    }

    __shared__ float sv[4][13];
    const int wid = threadIdx.x >> 6;
    if ((threadIdx.x & 63) == 0) {
        sv[wid][0] = mn1; sv[wid][1] = mn2; sv[wid][2] = mn3;
        sv[wid][3] = mx1; sv[wid][4] = mx2; sv[wid][5] = mx3;
        sv[wid][6] = P1;  sv[wid][7] = P2;  sv[wid][8] = P3;
        sv[wid][9] = Q1;  sv[wid][10] = Q2; sv[wid][11] = Q3;
        sv[wid][12] = R0;
    }
    __syncthreads();
    const int i = threadIdx.x;
    if (i < 13) {
        float v = sv[0][i];
        if (i < 3)      v = fminf(fminf(v, sv[1][i]), fminf(sv[2][i], sv[3][i]));
        else if (i < 6) v = fmaxf(fmaxf(v, sv[1][i]), fmaxf(sv[2][i], sv[3][i]));
        else            v = v + sv[1][i] + sv[2][i] + sv[3][i];
        part[(size_t)blockIdx.x * 16 + i] = v;   // plain store — NO atomics
    }
}

// One block reduces 4608 x 13 partials (295 KB, L2-warm) -> scalar loss.
// Threads 0..127 own batch-0 rows, 128..255 batch-1 (wave-pure batches).
__global__ __launch_bounds__(256, 1)
void k_final(const float* __restrict__ part, float* __restrict__ out) {
    const int t = threadIdx.x;
    const int batch = t >> 7;
    const int lane7 = t & 127;

    float mn[3] = {__uint_as_float(INF_BITS), __uint_as_float(INF_BITS), __uint_as_float(INF_BITS)};
    float mx[3] = {0.f, 0.f, 0.f};
    double P[3] = {0, 0, 0}, Q[3] = {0, 0, 0}, R0 = 0;

    for (int k = 0; k < HALFB / 128; k++) {   // 18 rows per thread
        const float4* r = (const float4*)(part + (size_t)(batch * HALFB + k * 128 + lane7) * 16);
        float4 r0 = r[0];  // mn1 mn2 mn3 mx1
        float4 r1 = r[1];  // mx2 mx3 P1  P2
        float4 r2 = r[2];  // P3  Q1  Q2  Q3
        float4 r3 = r[3];  // R0  -   -   -
        mn[0] = fminf(mn[0], r0.x); mn[1] = fminf(mn[1], r0.y); mn[2] = fminf(mn[2], r0.z);
        mx[0] = fmaxf(mx[0], r0.w); mx[1] = fmaxf(mx[1], r1.x); mx[2] = fmaxf(mx[2], r1.y);
        P[0] += (double)r1.z; P[1] += (double)r1.w; P[2] += (double)r2.x;
        Q[0] += (double)r2.y; Q[1] += (double)r2.z; Q[2] += (double)r2.w;
        R0 += (double)r3.x;
    }

    for (int off = 32; off; off >>= 1) {
#pragma unroll
        for (int j = 0; j < 3; j++) {
            mn[j] = fminf(mn[j], __shfl_down(mn[j], off, 64));
            mx[j] = fmaxf(mx[j], __shfl_down(mx[j], off, 64));
            P[j] += __shfl_down(P[j], off, 64);
            Q[j] += __shfl_down(Q[j], off, 64);
        }
        R0 += __shfl_down(R0, off, 64);
    }

    __shared__ float smn[4][3], smx[4][3];
    __shared__ double sP[4][3], sQ[4][3], sR[4];
    const int wid = t >> 6;
    if ((t & 63) == 0) {
#pragma unroll
        for (int j = 0; j < 3; j++) {
            smn[wid][j] = mn[j]; smx[wid][j] = mx[j];
            sP[wid][j] = P[j];   sQ[wid][j] = Q[j];
        }
        sR[wid] = R0;
    }
    __syncthreads();
    if (t == 0) {
        double acc = 0.0;
#pragma unroll
        for (int b = 0; b < 2; b++) {
            const int w0 = 2 * b, w1 = 2 * b + 1;
            acc += sR[w0] + sR[w1];
#pragma unroll
            for (int j = 0; j < 3; j++) {
                float mnf = fminf(smn[w0][j], smn[w1][j]);
                float mxf = fmaxf(smx[w0][j], smx[w1][j]);
                float sf = 1.0f / (mxf + EPSF - mnf);   // mirror reference fp32 scale
                acc += (double)sf * ((sP[w0][j] + sP[w1][j]) - (double)mnf * (sQ[w0][j] + sQ[w1][j]));
            }
        }
        out[0] = (float)(-acc / (double)NTOT);
    }
}

extern "C" void kernel_launch(void* const* d_in, const int* in_sizes, int n_in,
                              void* d_out, int out_size, void* d_ws, size_t ws_size,
                              hipStream_t stream) {
    const float* net = (const float*)d_in[0];   // [B, C, D, H, W] fp32
    const int* tgt = (const int*)d_in[1];       // [B, 1, D, H, W] int
    const float* dist = (const float*)d_in[2];  // [B, D, H, W] fp32
    float* part = (float*)d_ws;                 // 4608 x 16 floats = 295 KB

    k_fused<<<BLOCKS, TPB, 0, stream>>>(net, tgt, dist, part);
    k_final<<<1, 256, 0, stream>>>(part, (float*)d_out);
}